// Round 1
// baseline (1671.380 us; speedup 1.0000x reference)
//
#include <hip/hip_runtime.h>

#define NN 512
#define DIN 128
#define EE 32768
#define ETOT (EE + NN)   // 33280
#define HH 2
#define CC 200
#define HC 400
#define FC_OUT 1000
#define NEG 0.2f

// ---------------- workspace layout (float offsets) ----------------
#define OFF_XL   0
#define OFF_XR   204800
#define OFF_HB   409600
#define OFF_LOG  614400            // ETOT*2 = 66560 floats (logits -> alpha in place)
#define OFF_FCP  680960            // 1024 floats
#define OFF_INT  681984            // int region starts here (float-offset)
// int region (int offsets relative to int base):
#define IOFF_COUNTS  0             // 512
#define IOFF_ROWS    512           // 513
#define IOFF_CURSOR  1025          // 512
#define IOFF_CSRC    1537          // 33280
#define IOFF_CDST    34817         // 33280

// ---------------- CSR build ----------------
__global__ void count_kernel(const int* __restrict__ ei, int* __restrict__ counts) {
    int e = blockIdx.x * blockDim.x + threadIdx.x;
    if (e >= ETOT) return;
    int dst = (e < EE) ? ei[EE + e] : (e - EE);
    atomicAdd(&counts[dst], 1);
}

__global__ void scan_kernel(const int* __restrict__ counts, int* __restrict__ row_start,
                            int* __restrict__ cursor) {
    __shared__ int buf[NN];
    int tid = threadIdx.x;
    int c = counts[tid];
    buf[tid] = c;
    __syncthreads();
    for (int off = 1; off < NN; off <<= 1) {
        int v = (tid >= off) ? buf[tid - off] : 0;
        __syncthreads();
        buf[tid] += v;
        __syncthreads();
    }
    if (tid == 0) row_start[0] = 0;
    row_start[tid + 1] = buf[tid];
    cursor[tid] = buf[tid] - c;   // exclusive prefix
}

__global__ void scatter_kernel(const int* __restrict__ ei, int* __restrict__ cursor,
                               int* __restrict__ csr_src, int* __restrict__ csr_dst) {
    int e = blockIdx.x * blockDim.x + threadIdx.x;
    if (e >= ETOT) return;
    int src, dst;
    if (e < EE) { src = ei[e]; dst = ei[EE + e]; }
    else        { src = dst = e - EE; }
    int pos = atomicAdd(&cursor[dst], 1);
    csr_src[pos] = src;
    csr_dst[pos] = dst;
}

// ---------------- fused xl/xr GEMM: [512 x Din] @ [Din x 400] (x2) ----------------
// grid (7, 32), block (64, 4); each thread: 1 column j, 4 rows n
__global__ void gemm_lr(const float* __restrict__ h, int Din,
                        const float* __restrict__ Wl, const float* __restrict__ bl,
                        const float* __restrict__ Wr, const float* __restrict__ br,
                        float* __restrict__ xl, float* __restrict__ xr) {
    int j = blockIdx.x * 64 + threadIdx.x;
    int n0 = (blockIdx.y * blockDim.y + threadIdx.y) * 4;
    if (j >= HC) return;
    float accL[4] = {0.f, 0.f, 0.f, 0.f};
    float accR[4] = {0.f, 0.f, 0.f, 0.f};
    for (int k = 0; k < Din; ++k) {
        float wl = Wl[k * HC + j];
        float wr = Wr[k * HC + j];
#pragma unroll
        for (int t = 0; t < 4; ++t) {
            float hv = h[(n0 + t) * Din + k];
            accL[t] = fmaf(hv, wl, accL[t]);
            accR[t] = fmaf(hv, wr, accR[t]);
        }
    }
    float bL = bl[j], bR = br[j];
#pragma unroll
    for (int t = 0; t < 4; ++t) {
        xl[(n0 + t) * HC + j] = accL[t] + bL;
        xr[(n0 + t) * HC + j] = accR[t] + bR;
    }
}

// ---------------- per-edge logits: one wave per CSR slot ----------------
__global__ void logits_kernel(const float* __restrict__ xl, const float* __restrict__ xr,
                              const float* __restrict__ att,
                              const int* __restrict__ csr_src, const int* __restrict__ csr_dst,
                              float* __restrict__ logit) {
    int wid = threadIdx.x >> 6;
    int lane = threadIdx.x & 63;
    int s = blockIdx.x * 4 + wid;
    if (s >= ETOT) return;
    int src = csr_src[s], dst = csr_dst[s];
    const float* pl = xl + src * HC;
    const float* pr = xr + dst * HC;
    float p0 = 0.f, p1 = 0.f;
    for (int idx = lane; idx < HC; idx += 64) {
        float a = pl[idx] + pr[idx];
        float v = (a > 0.f) ? a : NEG * a;
        float w = v * att[idx];           // att flat [h*C + c] == channel index
        if (idx < CC) p0 += w; else p1 += w;
    }
#pragma unroll
    for (int m = 32; m >= 1; m >>= 1) {
        p0 += __shfl_xor(p0, m, 64);
        p1 += __shfl_xor(p1, m, 64);
    }
    if (lane == 0) { logit[s * 2] = p0; logit[s * 2 + 1] = p1; }
}

// ---------------- segment softmax: one wave per node, in-place logits -> alpha ----------------
__global__ void softmax_kernel(float* __restrict__ logit, const int* __restrict__ row_start) {
    int n = blockIdx.x;
    int lane = threadIdx.x;
    int s0 = row_start[n], s1 = row_start[n + 1];
    for (int h = 0; h < HH; ++h) {
        float m = -INFINITY;
        for (int s = s0 + lane; s < s1; s += 64)
            m = fmaxf(m, logit[s * 2 + h]);
#pragma unroll
        for (int k = 32; k >= 1; k >>= 1)
            m = fmaxf(m, __shfl_xor(m, k, 64));
        float sum = 0.f;
        for (int s = s0 + lane; s < s1; s += 64)
            sum += __expf(logit[s * 2 + h] - m);
#pragma unroll
        for (int k = 32; k >= 1; k >>= 1)
            sum += __shfl_xor(sum, k, 64);
        float inv = 1.0f / sum;
        for (int s = s0 + lane; s < s1; s += 64)
            logit[s * 2 + h] = __expf(logit[s * 2 + h] - m) * inv;
    }
}

// ---------------- aggregation: one block (256) per node ----------------
__global__ void aggregate_kernel(const float* __restrict__ alpha, const int* __restrict__ csr_src,
                                 const int* __restrict__ row_start, const float* __restrict__ xl,
                                 const float* __restrict__ b, float* __restrict__ hout,
                                 int do_relu) {
    int n = blockIdx.x;
    int tid = threadIdx.x;
    int s0 = row_start[n], s1 = row_start[n + 1];
    int h0 = (tid < CC) ? 0 : 1;
    float acc0 = 0.f, acc1 = 0.f;
    for (int s = s0; s < s1; ++s) {
        int src = csr_src[s];
        const float* row = xl + src * HC;
        float a0 = alpha[s * 2 + h0];
        acc0 = fmaf(a0, row[tid], acc0);
        if (tid < HC - 256) {                     // channels 256..399 -> head 1
            float a1 = alpha[s * 2 + 1];
            acc1 = fmaf(a1, row[tid + 256], acc1);
        }
    }
    float v0 = acc0 + b[tid];
    if (do_relu) v0 = fmaxf(v0, 0.f);
    hout[n * HC + tid] = v0;
    if (tid < HC - 256) {
        float v1 = acc1 + b[tid + 256];
        if (do_relu) v1 = fmaxf(v1, 0.f);
        hout[n * HC + tid + 256] = v1;
    }
}

// ---------------- FC head: split-K GEMV over fcW [204800 x 1000] ----------------
#define FC_CHUNKS 1024
#define FC_ROWS (NN * HC / FC_CHUNKS)   // 200
__global__ void fc_kernel(const float* __restrict__ flat, const float* __restrict__ fcW,
                          float* __restrict__ partial) {
    int t = threadIdx.x;
    if (t >= FC_OUT / 4) return;        // 250 active threads, 4 cols each
    int chunk = blockIdx.x;
    const int i0 = chunk * FC_ROWS;
    float4 acc = {0.f, 0.f, 0.f, 0.f};
#pragma unroll 4
    for (int r = 0; r < FC_ROWS; ++r) {
        int i = i0 + r;
        float f = flat[i];              // uniform -> scalar broadcast
        float4 w = reinterpret_cast<const float4*>(fcW + (size_t)i * FC_OUT)[t];
        acc.x = fmaf(f, w.x, acc.x);
        acc.y = fmaf(f, w.y, acc.y);
        acc.z = fmaf(f, w.z, acc.z);
        acc.w = fmaf(f, w.w, acc.w);
    }
    atomicAdd(&partial[4 * t + 0], acc.x);
    atomicAdd(&partial[4 * t + 1], acc.y);
    atomicAdd(&partial[4 * t + 2], acc.z);
    atomicAdd(&partial[4 * t + 3], acc.w);
}

__global__ void fc_fin(const float* __restrict__ partial, const float* __restrict__ fcb,
                       float* __restrict__ out) {
    int j = blockIdx.x * blockDim.x + threadIdx.x;
    if (j < FC_OUT) out[j] = fmaxf(partial[j] + fcb[j], 0.f);
}

// ---------------- launch ----------------
extern "C" void kernel_launch(void* const* d_in, const int* in_sizes, int n_in,
                              void* d_out, int out_size, void* d_ws, size_t ws_size,
                              hipStream_t stream) {
    const float* x  = (const float*)d_in[0];
    const int*   ei = (const int*)d_in[1];
    const float* Wl[3] = {(const float*)d_in[2],  (const float*)d_in[8],  (const float*)d_in[14]};
    const float* bl[3] = {(const float*)d_in[3],  (const float*)d_in[9],  (const float*)d_in[15]};
    const float* Wr[3] = {(const float*)d_in[4],  (const float*)d_in[10], (const float*)d_in[16]};
    const float* br[3] = {(const float*)d_in[5],  (const float*)d_in[11], (const float*)d_in[17]};
    const float* att[3]= {(const float*)d_in[6],  (const float*)d_in[12], (const float*)d_in[18]};
    const float* bb[3] = {(const float*)d_in[7],  (const float*)d_in[13], (const float*)d_in[19]};
    const float* fcW = (const float*)d_in[20];
    const float* fcb = (const float*)d_in[21];
    float* out = (float*)d_out;

    float* wsf = (float*)d_ws;
    float* xl   = wsf + OFF_XL;
    float* xr   = wsf + OFF_XR;
    float* hbuf = wsf + OFF_HB;
    float* lg   = wsf + OFF_LOG;
    float* fcp  = wsf + OFF_FCP;
    int* ib       = (int*)(wsf + OFF_INT);
    int* counts   = ib + IOFF_COUNTS;
    int* row_start= ib + IOFF_ROWS;
    int* cursor   = ib + IOFF_CURSOR;
    int* csr_src  = ib + IOFF_CSRC;
    int* csr_dst  = ib + IOFF_CDST;

    // CSR build (edge structure constant across layers)
    hipMemsetAsync(counts, 0, NN * sizeof(int), stream);
    count_kernel<<<(ETOT + 255) / 256, 256, 0, stream>>>(ei, counts);
    scan_kernel<<<1, NN, 0, stream>>>(counts, row_start, cursor);
    scatter_kernel<<<(ETOT + 255) / 256, 256, 0, stream>>>(ei, cursor, csr_src, csr_dst);

    // 3 GATv2 layers
    for (int l = 0; l < 3; ++l) {
        const float* hin = (l == 0) ? x : hbuf;
        int Din = (l == 0) ? DIN : HC;
        gemm_lr<<<dim3(7, 32), dim3(64, 4), 0, stream>>>(hin, Din, Wl[l], bl[l], Wr[l], br[l], xl, xr);
        logits_kernel<<<ETOT / 4, 256, 0, stream>>>(xl, xr, att[l], csr_src, csr_dst, lg);
        softmax_kernel<<<NN, 64, 0, stream>>>(lg, row_start);
        aggregate_kernel<<<NN, 256, 0, stream>>>(lg, csr_src, row_start, xl, bb[l], hbuf,
                                                 (l != 2) ? 1 : 0);
    }

    // FC head
    hipMemsetAsync(fcp, 0, FC_OUT * sizeof(float), stream);
    fc_kernel<<<FC_CHUNKS, 256, 0, stream>>>(hbuf, fcW, fcp);
    fc_fin<<<4, 256, 0, stream>>>(fcp, fcb, out);
}